// Round 10
// baseline (51.410 us; speedup 1.0000x reference)
//
#include <hip/hip_runtime.h>

// B*H*W = 65536 vectors, dim 64, 512 codes
#define NVEC 65536
#define DIM 64
#define KCODES 512
#define VPB 128       // vectors per block
#define NBLK 512      // NVEC / VPB
#define ELS 2048.0f   // residual pre-scale (avoids fp16 denormals)
#define INV_ELS (1.0f / 2048.0f)
#define GAP_THR 2e-4f // rescore guard: >> max split-fp16 ordering error (~1.5e-5)

typedef _Float16 f16x8 __attribute__((ext_vector_type(8)));
typedef float    f32x4 __attribute__((ext_vector_type(4)));

// ws layout (floats):
#define WS_EN   4                   // [4..516) codebook norms
#define WS_EH   1024                // [1024..17408) hi fp16 B-fragments
#define WS_EL   (1024 + 16384)      // [17408..33792) residual fp16 B-fragments
#define WS_PART 33792               // [33792..34304) per-block loss partials
#define WS_EMBT 34816               // [34816..67584) embT[k][d]

// Prep (17 blocks x 512): b=0 norms; b=1..8 MFMA B-fragments (hi + scaled
// residual); b=9..16 transpose emb -> embT[k][d] via LDS tile.
__global__ __launch_bounds__(512, 1) void prep_kernel(const float* __restrict__ emb,
                                                      float* __restrict__ ws) {
    const int tid = threadIdx.x;
    const int b   = blockIdx.x;
    if (b == 0) {
        float s = 0.f;
#pragma unroll
        for (int d = 0; d < DIM; ++d) { float v = emb[d * KCODES + tid]; s = fmaf(v, v, s); }
        ws[WS_EN + tid] = s;
    } else if (b <= 8) {
        const int fl = (b - 1) * 512 + tid;            // fragment-lane id, 0..4095
        const int ct = fl >> 7, s5 = (fl >> 6) & 1, l = fl & 63;
        const int k  = ct * 16 + (l & 15);             // B col
        const int d0 = s5 * 32 + (l >> 4) * 8;         // B k-rows (d)
        f16x8 eh, el;
#pragma unroll
        for (int e = 0; e < 8; ++e) {
            float v = emb[(d0 + e) * KCODES + k];
            _Float16 h = (_Float16)v;
            eh[e] = h;
            el[e] = (_Float16)((v - (float)h) * ELS);
        }
        ((f16x8*)(ws + WS_EH))[fl] = eh;
        ((f16x8*)(ws + WS_EL))[fl] = el;
    } else {
        __shared__ float tl[64][65];
        const int kt = b - 9;          // k-tile 0..7
        const int r  = tid >> 3;       // 0..63
        const int g  = tid & 7;
#pragma unroll
        for (int i = 0; i < 8; ++i)
            tl[r][g * 8 + i] = emb[r * KCODES + kt * 64 + g * 8 + i];
        __syncthreads();
#pragma unroll
        for (int i = 0; i < 8; ++i)
            ws[WS_EMBT + (kt * 64 + r) * 64 + g * 8 + i] = tl[g * 8 + i][r];
    }
}

// Main: 512 thr = 8 waves, 128 vectors/block, grid 512 = 2 blocks/CU (all
// co-resident). Wave owns 16 vectors, scans all 512 codes. B-fragments are
// staged ONCE per block into LDS (double-buffered 4-tile chunks; global->reg
// issued a chunk early, ds_write after barrier) and shared by all 8 waves:
// 8x less L2 traffic than per-wave register streams. Approx score is zn-free
// (ordering-invariant); slim float top-2 with explicit k tracking; exact
// fp32 rescore only when approx gap <= GAP_THR. No atomics.
__global__ __launch_bounds__(512, 2) void vq_kernel(const float* __restrict__ x,
                                                    const float* __restrict__ ws_ro,
                                                    float* __restrict__ out,
                                                    float* __restrict__ part) {
    // 32 KB overlay: prologue zh/zl tiles, then B-fragment staging buffers
    __shared__ alignas(16) unsigned char ovlRaw[32768];
    f16x8 (*zhS)[8] = reinterpret_cast<f16x8(*)[8]>(ovlRaw);            // [128][8]
    f16x8 (*zlS)[8] = reinterpret_cast<f16x8(*)[8]>(ovlRaw + 16384);    // [128][8]
    f16x8* stgS     = reinterpret_cast<f16x8*>(ovlRaw);                 // [2][2][512]
    __shared__ float enS[KCODES];
    __shared__ int   cand[VPB][2];
    __shared__ float sdf[VPB][2];
    __shared__ float exd[VPB][2];
    __shared__ int   bksel[VPB];
    __shared__ float swl[8];

    const int tid  = threadIdx.x;
    const int wid  = tid >> 6;            // 0..7
    const int lane = tid & 63;
    const size_t xbase = (size_t)blockIdx.x * VPB * DIM;

    const f16x8* ehp = (const f16x8*)(ws_ro + WS_EH);
    const f16x8* elp = (const f16x8*)(ws_ro + WS_EL);

    // issue chunk-0 staging loads FIRST (latency hides under prologue)
    f16x8 pgh = ehp[tid];                 // rows 0..7 of eh   (tid = r*64+l)
    f16x8 pgl = elp[tid];

    enS[tid] = ws_ro[WS_EN + tid];        // 512 threads, one code each

    // x-block -> fp16 hi + scaled residual into swizzled LDS
    {
        const int v  = tid >> 2;          // 0..127
        const int d0 = (tid & 3) * 16;
        const float* xp = x + xbase + v * DIM + d0;
        float4 a = *(const float4*)(xp);
        float4 b = *(const float4*)(xp + 4);
        float4 c = *(const float4*)(xp + 8);
        float4 e = *(const float4*)(xp + 12);
        float t0[8] = {a.x, a.y, a.z, a.w, b.x, b.y, b.z, b.w};
        float t1[8] = {c.x, c.y, c.z, c.w, e.x, e.y, e.z, e.w};
        f16x8 h0, l0, h1, l1;
#pragma unroll
        for (int i = 0; i < 8; ++i) {
            _Float16 h = (_Float16)t0[i]; h0[i] = h; l0[i] = (_Float16)((t0[i] - (float)h) * ELS);
            _Float16 g = (_Float16)t1[i]; h1[i] = g; l1[i] = (_Float16)((t1[i] - (float)g) * ELS);
        }
        const int u0 = ((d0 >> 3))     ^ (v & 7);
        const int u1 = ((d0 >> 3) + 1) ^ (v & 7);
        zhS[v][u0] = h0; zhS[v][u1] = h1;
        zlS[v][u0] = l0; zlS[v][u1] = l1;
    }
    __syncthreads();

    // A-fragments: row = lane&15 (vector), k = (lane>>4)*8 + e (+32 for s=1)
    const int vb = wid * 16;
    const int vA = vb + (lane & 15);
    const int g4 = lane >> 4;
    const int sw = vA & 7;
    f16x8 ah0 = zhS[vA][(g4)     ^ sw];
    f16x8 ah1 = zhS[vA][(4 + g4) ^ sw];
    f16x8 al0 = zlS[vA][(g4)     ^ sw];
    f16x8 al1 = zlS[vA][(4 + g4) ^ sw];
    __syncthreads();                      // all zh/zl reads done -> overlay reusable

    // write chunk 0 into staging buffer 0
    stgS[tid]       = pgh;
    stgS[512 + tid] = pgl;
    __syncthreads();

    float best[4]  = {3.4e38f, 3.4e38f, 3.4e38f, 3.4e38f};
    float best2[4] = {3.4e38f, 3.4e38f, 3.4e38f, 3.4e38f};
    int   bk1[4]   = {0, 0, 0, 0};
    int   bk2[4]   = {0, 0, 0, 0};

#pragma unroll 1
    for (int c = 0; c < 8; ++c) {
        const int buf = (c & 1) * 1024;
        f16x8 ngh, ngl;
        if (c < 7) {                      // prefetch chunk c+1 (T14 issue-early)
            ngh = ehp[(c + 1) * 512 + tid];
            ngl = elp[(c + 1) * 512 + tid];
        }
#pragma unroll
        for (int lt = 0; lt < 4; ++lt) {
            const int ct = c * 4 + lt;
            f16x8 bh0 = stgS[buf + (2 * lt)     * 64 + lane];
            f16x8 bh1 = stgS[buf + (2 * lt + 1) * 64 + lane];
            f16x8 bl0 = stgS[buf + 512 + (2 * lt)     * 64 + lane];
            f16x8 bl1 = stgS[buf + 512 + (2 * lt + 1) * 64 + lane];
            f32x4 acch = {0.f, 0.f, 0.f, 0.f};
            f32x4 accm = {0.f, 0.f, 0.f, 0.f};
            acch = __builtin_amdgcn_mfma_f32_16x16x32_f16(ah0, bh0, acch, 0, 0, 0);
            acch = __builtin_amdgcn_mfma_f32_16x16x32_f16(ah1, bh1, acch, 0, 0, 0);
            accm = __builtin_amdgcn_mfma_f32_16x16x32_f16(al0, bh0, accm, 0, 0, 0);
            accm = __builtin_amdgcn_mfma_f32_16x16x32_f16(al1, bh1, accm, 0, 0, 0);
            accm = __builtin_amdgcn_mfma_f32_16x16x32_f16(ah0, bl0, accm, 0, 0, 0);
            accm = __builtin_amdgcn_mfma_f32_16x16x32_f16(ah1, bl1, accm, 0, 0, 0);
            const int   kk  = ct * 16 + (lane & 15);   // C/D col = lane&15
            const float enk = enS[kk];
#pragma unroll
            for (int j = 0; j < 4; ++j) {
                // zn-free approx score: en[k] - 2*dot (ordering-equivalent)
                float dot = fmaf(accm[j], INV_ELS, acch[j]);
                float sc  = fmaf(-2.0f, dot, enk);
                bool  c1  = sc < best[j];
                bool  c2  = sc < best2[j];
                bk2[j]    = c1 ? bk1[j] : (c2 ? kk : bk2[j]);
                best2[j]  = fminf(best2[j], fmaxf(sc, best[j]));
                bk1[j]    = c1 ? kk : bk1[j];
                best[j]   = fminf(sc, best[j]);
            }
        }
        __syncthreads();                  // everyone done reading buf
        if (c < 7) {
            const int nbuf = ((c + 1) & 1) * 1024;
            stgS[nbuf + tid]       = ngh;
            stgS[nbuf + 512 + tid] = ngl;
        }
        __syncthreads();                  // chunk c+1 ready
    }

    // top-2 (with indices) merge across the 16 lanes sharing each vector row
#pragma unroll
    for (int m = 1; m <= 8; m <<= 1) {
#pragma unroll
        for (int j = 0; j < 4; ++j) {
            float qb  = __shfl_xor(best[j],  m);
            int   qk  = __shfl_xor(bk1[j],   m);
            float q2  = __shfl_xor(best2[j], m);
            int   qk2 = __shfl_xor(bk2[j],   m);
            bool  t1  = (qb < best[j]) || (qb == best[j] && qk < bk1[j]);
            float lb  = t1 ? best[j] : qb;      // losing first
            int   lk  = t1 ? bk1[j]  : qk;
            float nb  = t1 ? qb : best[j];      // winning first
            int   nk  = t1 ? qk : bk1[j];
            bool  ta  = (best2[j] < q2) || (best2[j] == q2 && bk2[j] < qk2);
            float sb  = ta ? best2[j] : q2;
            int   sk  = ta ? bk2[j]   : qk2;
            bool  tb  = (lb < sb) || (lb == sb && lk < sk);
            best2[j]  = tb ? lb : sb;
            bk2[j]    = tb ? lk : sk;
            best[j]   = nb;
            bk1[j]    = nk;
        }
    }
    {
        const int j = lane & 15;
        if (j < 4) {
            const int v = vb + g4 * 4 + j;
            cand[v][0] = bk1[j];
            cand[v][1] = bk2[j];
            sdf[v][0]  = best[j];
            sdf[v][1]  = best2[j];
        }
    }
    __syncthreads();

    // conditional exact rescore (reference-exact chain; zn computed inline)
    if (tid < 256) {
        const int v = tid >> 1, cc = tid & 1;
        float res = sdf[v][cc];
        if (sdf[v][1] - sdf[v][0] <= GAP_THR) {
            const int k = cand[v][cc];
            const float* xr = x + xbase + v * DIM;
            const float* er = ws_ro + WS_EMBT + k * 64;
            float zn = 0.f, dot = 0.f;
#pragma unroll
            for (int d = 0; d < DIM; ++d) {
                float xv = xr[d];
                zn  = fmaf(xv, xv, zn);
                dot = fmaf(xv, er[d], dot);
            }
            res = fmaf(-2.0f, dot, zn + enS[k]);
        }
        exd[v][cc] = res;
    }
    __syncthreads();
    if (tid < VPB) {
        const int k0 = cand[tid][0], k1 = cand[tid][1];
        const float d0 = exd[tid][0], d1 = exd[tid][1];
        const bool take2 = (d1 < d0) || (d1 == d0 && k1 < k0);
        bksel[tid] = take2 ? k1 : k0;
    }
    __syncthreads();

    // epilogue: thread -> (vector v16, dim-block j16); q from embT rows
    const int v16 = tid >> 2;             // 0..127
    const int j16 = (tid & 3) * 16;
    const int bk  = bksel[v16];
    const int gvec = blockIdx.x * VPB + v16;
    const float*  xg  = x + (size_t)gvec * DIM + j16;
    float*        og  = out + (size_t)gvec * DIM + j16;
    const float4* et4 = (const float4*)(ws_ro + WS_EMBT + bk * 64);

    float lossLocal = 0.f;
#pragma unroll
    for (int c = 0; c < 4; ++c) {
        float4 q  = et4[(tid & 3) * 4 + c];
        *(float4*)(og + c * 4) = q;
        float4 xa = *(const float4*)(xg + c * 4);
        float a;
        a = q.x - xa.x; lossLocal = fmaf(a, a, lossLocal);
        a = q.y - xa.y; lossLocal = fmaf(a, a, lossLocal);
        a = q.z - xa.z; lossLocal = fmaf(a, a, lossLocal);
        a = q.w - xa.w; lossLocal = fmaf(a, a, lossLocal);
    }

    // block-reduce loss -> one partial store per block
#pragma unroll
    for (int off = 32; off; off >>= 1) lossLocal += __shfl_down(lossLocal, off, 64);
    if (lane == 0) swl[wid] = lossLocal;
    __syncthreads();
    if (tid == 0) {
        float s = 0.f;
#pragma unroll
        for (int i = 0; i < 8; ++i) s += swl[i];
        part[WS_PART + blockIdx.x] = s;
    }
}

// Finish: reduce 512 per-block partials, write the loss element.
__global__ __launch_bounds__(256, 1) void finish_kernel(const float* __restrict__ part,
                                                        float* __restrict__ out) {
    __shared__ float sw[4];
    const int tid = threadIdx.x, lane = tid & 63, wid = tid >> 6;
    float s = part[WS_PART + tid] + part[WS_PART + tid + 256];
#pragma unroll
    for (int off = 32; off; off >>= 1) s += __shfl_down(s, off, 64);
    if (lane == 0) sw[wid] = s;
    __syncthreads();
    if (tid == 0) {
        float total = sw[0] + sw[1] + sw[2] + sw[3];
        out[(size_t)NVEC * DIM] = 2.0f * total / (float)((size_t)NVEC * DIM);
    }
}

extern "C" void kernel_launch(void* const* d_in, const int* in_sizes, int n_in,
                              void* d_out, int out_size, void* d_ws, size_t ws_size,
                              hipStream_t stream) {
    const float* x   = (const float*)d_in[0];
    const float* emb = (const float*)d_in[1];
    float* out = (float*)d_out;
    float* ws  = (float*)d_ws;

    prep_kernel<<<dim3(17), dim3(512), 0, stream>>>(emb, ws);
    vq_kernel<<<dim3(NBLK), dim3(512), 0, stream>>>(x, ws, out, ws);
    finish_kernel<<<dim3(1), dim3(256), 0, stream>>>(ws, out);
}